// Round 1
// baseline (2201.491 us; speedup 1.0000x reference)
//
#include <hip/hip_runtime.h>

#define N_NODES 100000
#define F_IN 512
#define HID 16
#define CLS 7

// ---------------------------------------------------------------------------
// Edge-index dtype detection: reference uses int64, harness doc claims int32.
// Under int64 (values < 2^31, little-endian) every odd int32 slot is the
// zero high word. Under int32 the odd slots are random node ids (OR != 0).
// ---------------------------------------------------------------------------
__global__ void detect_i64_kernel(const unsigned int* __restrict__ idx32,
                                  int* __restrict__ flag, int n_check) {
    __shared__ unsigned int s;
    if (threadIdx.x == 0) s = 0u;
    __syncthreads();
    unsigned int v = 0u;
    for (int i = threadIdx.x; i < n_check; i += blockDim.x)
        v |= idx32[2 * i + 1];
    atomicOr(&s, v);
    __syncthreads();
    if (threadIdx.x == 0) *flag = (s == 0u) ? 1 : 0;
}

__device__ __forceinline__ void get_edge(const void* eidx, long long E,
                                         long long e, int is64,
                                         int& s, int& d) {
    if (is64) {
        const long long* p = (const long long*)eidx;
        s = (int)p[e];
        d = (int)p[E + e];
    } else {
        const int* p = (const int*)eidx;
        s = p[e];
        d = p[E + e];
    }
}

// ---------------------------------------------------------------------------
// Degree (in-degree over dst) + dinv = rsqrt(deg + 1 self-loop)
// ---------------------------------------------------------------------------
__global__ void deg_kernel(const void* __restrict__ eidx, long long E,
                           const int* __restrict__ flag, int* __restrict__ deg) {
    const int is64 = *flag;
    long long i = (long long)blockIdx.x * blockDim.x + threadIdx.x;
    if (i >= E) return;
    int d;
    if (is64) d = (int)((const long long*)eidx)[E + i];
    else      d = ((const int*)eidx)[E + i];
    atomicAdd(&deg[d], 1);
}

__global__ void dinv_kernel(const int* __restrict__ deg, float* __restrict__ dinv) {
    int i = blockIdx.x * blockDim.x + threadIdx.x;
    if (i >= N_NODES) return;
    dinv[i] = rsqrtf((float)(deg[i] + 1));
}

// ---------------------------------------------------------------------------
// GEMM1: h1[N][16] = x[N][512] @ W1[512][16]   (fp32, memory-bound on x)
// Block: 256 threads = 64 rows x 4 j-groups; W1 fully in LDS (32KB),
// x staged in 64x64 chunks (17KB padded). 4 fp32 acc / thread.
// ---------------------------------------------------------------------------
#define G1_ROWS 64
#define G1_KC 64

__global__ __launch_bounds__(256) void gemm1_kernel(const float* __restrict__ x,
                                                    const float* __restrict__ W1,
                                                    float* __restrict__ h1) {
    __shared__ float Ws[F_IN * HID];            // [k][j], 32 KB
    __shared__ float xs[G1_ROWS][G1_KC + 4];    // +4 pad: 2-way banks max (free)
    const int tid = threadIdx.x;
    const int rowBase = blockIdx.x * G1_ROWS;

    // Load all of W1 (2048 float4s, coalesced)
#pragma unroll
    for (int it = 0; it < 8; it++) {
        int f = it * 256 + tid;
        ((float4*)Ws)[f] = ((const float4*)W1)[f];
    }

    const int r  = tid >> 2;          // local row 0..63
    const int j4 = tid & 3;           // float4 column group 0..3
    float4 acc = make_float4(0.f, 0.f, 0.f, 0.f);

    for (int kc = 0; kc < F_IN; kc += G1_KC) {
        __syncthreads();
        // stage 64 rows x 64 cols of x (1024 float4s, coalesced 256B runs)
#pragma unroll
        for (int it = 0; it < 4; it++) {
            int f = it * 256 + tid;     // float4 index
            int row = f >> 4;           // 16 float4 per row
            int c4 = f & 15;
            int grow = rowBase + row;
            if (grow >= N_NODES) grow = N_NODES - 1;   // clamp (stores guarded)
            float4 v = ((const float4*)(x + (long long)grow * F_IN + kc))[c4];
            *((float4*)&xs[row][c4 * 4]) = v;
        }
        __syncthreads();
#pragma unroll
        for (int k = 0; k < G1_KC; k++) {
            float xv = xs[r][k];
            float4 wv = ((const float4*)(Ws + (kc + k) * HID))[j4];
            acc.x += xv * wv.x;
            acc.y += xv * wv.y;
            acc.z += xv * wv.z;
            acc.w += xv * wv.w;
        }
    }
    int grow = rowBase + r;
    if (grow < N_NODES)
        ((float4*)(h1 + (long long)grow * HID))[j4] = acc;   // coalesced
}

// ---------------------------------------------------------------------------
// Layer-1 aggregation init: agg1[i][j] = b1[j] + h1[i][j] * dinv[i]^2
// (self-loop + bias; also overwrites the 0xAA poison)
// ---------------------------------------------------------------------------
__global__ void init1_kernel(const float* __restrict__ h1,
                             const float* __restrict__ dinv,
                             const float* __restrict__ b1,
                             float* __restrict__ agg1) {
    int gid = blockIdx.x * blockDim.x + threadIdx.x;   // over N*4 float4s
    if (gid >= N_NODES * 4) return;
    int i = gid >> 2, jg = gid & 3;
    float di = dinv[i];
    float w = di * di;
    float4 hv = ((const float4*)h1)[(long long)i * 4 + jg];
    float4 bv = ((const float4*)b1)[jg];
    float4 o;
    o.x = bv.x + hv.x * w;
    o.y = bv.y + hv.y * w;
    o.z = bv.z + hv.z * w;
    o.w = bv.w + hv.w * w;
    ((float4*)agg1)[(long long)i * 4 + jg] = o;
}

// ---------------------------------------------------------------------------
// Layer-1 edge scatter: agg1[dst][:] += h1[src][:] * dinv[src]*dinv[dst]
// 4 threads per edge (one float4 each) -> 4 fp32 atomics per thread.
// ---------------------------------------------------------------------------
__global__ void agg1_kernel(const void* __restrict__ eidx, long long E,
                            const int* __restrict__ flag,
                            const float* __restrict__ h1,
                            const float* __restrict__ dinv,
                            float* __restrict__ agg1) {
    const int is64 = *flag;
    long long gid = (long long)blockIdx.x * blockDim.x + threadIdx.x;
    if (gid >= 4 * E) return;
    long long e = gid >> 2;
    int jg = (int)(gid & 3);
    int s, d;
    get_edge(eidx, E, e, is64, s, d);
    float w = dinv[s] * dinv[d];
    float4 hv = ((const float4*)h1)[(long long)s * 4 + jg];
    float* op = agg1 + (long long)d * HID + jg * 4;
    unsafeAtomicAdd(op + 0, hv.x * w);
    unsafeAtomicAdd(op + 1, hv.y * w);
    unsafeAtomicAdd(op + 2, hv.z * w);
    unsafeAtomicAdd(op + 3, hv.w * w);
}

// ---------------------------------------------------------------------------
// Fused relu + GEMM2 + layer-2 init:
//   h2[i][c]  = sum_j relu(agg1[i][j]) * W2[j][c]
//   out[i][c] = b2[c] + h2[i][c] * dinv[i]^2
// W2/b2 indices are uniform -> compiler scalarizes to s_load.
// ---------------------------------------------------------------------------
__global__ void gemm2_relu_kernel(const float* __restrict__ agg1,
                                  const float* __restrict__ W2,
                                  const float* __restrict__ b2,
                                  const float* __restrict__ dinv,
                                  float* __restrict__ h2,
                                  float* __restrict__ out) {
    int i = blockIdx.x * blockDim.x + threadIdx.x;
    if (i >= N_NODES) return;
    const float4* a4 = (const float4*)agg1 + (long long)i * 4;
    float4 v0 = a4[0], v1 = a4[1], v2 = a4[2], v3 = a4[3];
    float hr[16];
    hr[0] = fmaxf(v0.x, 0.f);  hr[1] = fmaxf(v0.y, 0.f);
    hr[2] = fmaxf(v0.z, 0.f);  hr[3] = fmaxf(v0.w, 0.f);
    hr[4] = fmaxf(v1.x, 0.f);  hr[5] = fmaxf(v1.y, 0.f);
    hr[6] = fmaxf(v1.z, 0.f);  hr[7] = fmaxf(v1.w, 0.f);
    hr[8] = fmaxf(v2.x, 0.f);  hr[9] = fmaxf(v2.y, 0.f);
    hr[10] = fmaxf(v2.z, 0.f); hr[11] = fmaxf(v2.w, 0.f);
    hr[12] = fmaxf(v3.x, 0.f); hr[13] = fmaxf(v3.y, 0.f);
    hr[14] = fmaxf(v3.z, 0.f); hr[15] = fmaxf(v3.w, 0.f);
    float di = dinv[i];
    float w = di * di;
#pragma unroll
    for (int c = 0; c < CLS; c++) {
        float acc = 0.f;
#pragma unroll
        for (int j = 0; j < HID; j++) acc += hr[j] * W2[j * CLS + c];
        h2[(long long)i * CLS + c] = acc;
        out[(long long)i * CLS + c] = b2[c] + acc * w;
    }
}

// ---------------------------------------------------------------------------
// Layer-2 edge scatter: out[dst][:] += h2[src][:] * dinv[src]*dinv[dst]
// ---------------------------------------------------------------------------
__global__ void agg2_kernel(const void* __restrict__ eidx, long long E,
                            const int* __restrict__ flag,
                            const float* __restrict__ h2,
                            const float* __restrict__ dinv,
                            float* __restrict__ out) {
    const int is64 = *flag;
    long long e = (long long)blockIdx.x * blockDim.x + threadIdx.x;
    if (e >= E) return;
    int s, d;
    get_edge(eidx, E, e, is64, s, d);
    float w = dinv[s] * dinv[d];
    const float* hp = h2 + (long long)s * CLS;
    float* op = out + (long long)d * CLS;
#pragma unroll
    for (int c = 0; c < CLS; c++)
        unsafeAtomicAdd(op + c, hp[c] * w);
}

// ---------------------------------------------------------------------------
extern "C" void kernel_launch(void* const* d_in, const int* in_sizes, int n_in,
                              void* d_out, int out_size, void* d_ws, size_t ws_size,
                              hipStream_t stream) {
    const float* x   = (const float*)d_in[0];
    const void*  eidx = d_in[1];
    const float* W1  = (const float*)d_in[2];
    const float* b1  = (const float*)d_in[3];
    const float* W2  = (const float*)d_in[4];
    const float* b2  = (const float*)d_in[5];
    float* out = (float*)d_out;
    const long long E = (long long)in_sizes[1] / 2;

    // workspace carve-up (256B aligned); total ~16.5 MB
    char* ws = (char*)d_ws;
    size_t off = 0;
    auto alloc = [&](size_t bytes) -> void* {
        void* p = ws + off;
        off = (off + bytes + 255) & ~(size_t)255;
        return p;
    };
    int*   flag = (int*)alloc(4);
    int*   deg  = (int*)alloc((size_t)N_NODES * 4);
    float* dinv = (float*)alloc((size_t)N_NODES * 4);
    float* h1   = (float*)alloc((size_t)N_NODES * HID * 4);
    float* agg1 = (float*)alloc((size_t)N_NODES * HID * 4);
    float* h2   = (float*)alloc((size_t)N_NODES * CLS * 4);
    (void)ws_size;

    hipMemsetAsync(deg, 0, (size_t)N_NODES * 4, stream);

    detect_i64_kernel<<<1, 256, 0, stream>>>((const unsigned int*)eidx, flag, 4096);

    deg_kernel<<<(int)((E + 255) / 256), 256, 0, stream>>>(eidx, E, flag, deg);

    dinv_kernel<<<(N_NODES + 255) / 256, 256, 0, stream>>>(deg, dinv);

    gemm1_kernel<<<(N_NODES + G1_ROWS - 1) / G1_ROWS, 256, 0, stream>>>(x, W1, h1);

    init1_kernel<<<(N_NODES * 4 + 255) / 256, 256, 0, stream>>>(h1, dinv, b1, agg1);

    agg1_kernel<<<(int)((4 * E + 255) / 256), 256, 0, stream>>>(eidx, E, flag, h1, dinv, agg1);

    gemm2_relu_kernel<<<(N_NODES + 255) / 256, 256, 0, stream>>>(agg1, W2, b2, dinv, h2, out);

    agg2_kernel<<<(int)((E + 255) / 256), 256, 0, stream>>>(eidx, E, flag, h2, dinv, out);
}

// Round 2
// 836.586 us; speedup vs baseline: 2.6315x; 2.6315x over previous
//
#include <hip/hip_runtime.h>

#define N_NODES 100000
#define F_IN 512
#define HID 16
#define CLS 7

// ---------------------------------------------------------------------------
// Edge-index dtype detection: reference uses int64, harness doc claims int32.
// Under int64 (values < 2^31, little-endian) every odd int32 slot is the
// zero high word. Under int32 the odd slots are random node ids (OR != 0).
// ---------------------------------------------------------------------------
__global__ void detect_i64_kernel(const unsigned int* __restrict__ idx32,
                                  int* __restrict__ flag, int n_check) {
    __shared__ unsigned int s;
    if (threadIdx.x == 0) s = 0u;
    __syncthreads();
    unsigned int v = 0u;
    for (int i = threadIdx.x; i < n_check; i += blockDim.x)
        v |= idx32[2 * i + 1];
    atomicOr(&s, v);
    __syncthreads();
    if (threadIdx.x == 0) *flag = (s == 0u) ? 1 : 0;
}

__device__ __forceinline__ void get_edge(const void* eidx, long long E,
                                         long long e, int is64,
                                         int& s, int& d) {
    if (is64) {
        const long long* p = (const long long*)eidx;
        s = (int)p[e];
        d = (int)p[E + e];
    } else {
        const int* p = (const int*)eidx;
        s = p[e];
        d = p[E + e];
    }
}

// ---------------------------------------------------------------------------
// In-degree histogram over dst (int atomics — cheap, unlike fp32)
// ---------------------------------------------------------------------------
__global__ void deg_kernel(const void* __restrict__ eidx, long long E,
                           const int* __restrict__ flag, int* __restrict__ deg) {
    const int is64 = *flag;
    long long i = (long long)blockIdx.x * blockDim.x + threadIdx.x;
    if (i >= E) return;
    int d;
    if (is64) d = (int)((const long long*)eidx)[E + i];
    else      d = ((const int*)eidx)[E + i];
    atomicAdd(&deg[d], 1);
}

__global__ void dinv_kernel(const int* __restrict__ deg, float* __restrict__ dinv) {
    int i = blockIdx.x * blockDim.x + threadIdx.x;
    if (i >= N_NODES) return;
    dinv[i] = rsqrtf((float)(deg[i] + 1));   // +1 self-loop
}

// ---------------------------------------------------------------------------
// Exclusive scan of deg[N] -> rowptr[N+1]  (3-kernel classic)
// ---------------------------------------------------------------------------
#define SCAN_B 1024

__global__ __launch_bounds__(SCAN_B) void scan1_kernel(const int* __restrict__ deg,
                                                       int* __restrict__ tmp,
                                                       int* __restrict__ bsum, int n) {
    __shared__ int s[SCAN_B];
    int tid = threadIdx.x;
    int i = blockIdx.x * SCAN_B + tid;
    int v = (i < n) ? deg[i] : 0;
    s[tid] = v;
    __syncthreads();
#pragma unroll
    for (int off = 1; off < SCAN_B; off <<= 1) {
        int add = (tid >= off) ? s[tid - off] : 0;
        __syncthreads();
        s[tid] += add;
        __syncthreads();
    }
    if (i < n) tmp[i] = s[tid];                  // inclusive scan within block
    if (tid == SCAN_B - 1) bsum[blockIdx.x] = s[tid];
}

__global__ void scan2_kernel(int* __restrict__ bsum, int nb, int* __restrict__ rowptr_last) {
    // single thread: exclusive scan of 98 block sums
    int running = 0;
    for (int b = 0; b < nb; b++) {
        int t = bsum[b];
        bsum[b] = running;
        running += t;
    }
    *rowptr_last = running;   // rowptr[N] = E
}

__global__ __launch_bounds__(SCAN_B) void scan3_kernel(const int* __restrict__ deg,
                                                       const int* __restrict__ tmp,
                                                       const int* __restrict__ bsum,
                                                       int* __restrict__ rowptr, int n) {
    int i = blockIdx.x * SCAN_B + threadIdx.x;
    if (i >= n) return;
    rowptr[i] = tmp[i] - deg[i] + bsum[blockIdx.x];   // exclusive
}

// ---------------------------------------------------------------------------
// Fill CSR: csr_src[pos] = src, pos = cursor[dst]++  (int atomics only)
// ---------------------------------------------------------------------------
__global__ void fill_kernel(const void* __restrict__ eidx, long long E,
                            const int* __restrict__ flag,
                            int* __restrict__ cursor, int* __restrict__ csr_src) {
    const int is64 = *flag;
    long long e = (long long)blockIdx.x * blockDim.x + threadIdx.x;
    if (e >= E) return;
    int s, d;
    get_edge(eidx, E, e, is64, s, d);
    int pos = atomicAdd(&cursor[d], 1);
    csr_src[pos] = s;
}

// ---------------------------------------------------------------------------
// GEMM1: h1s[i][16] = (x[i][512] @ W1[512][16]) * dinv[i]   (fp32, HBM-bound)
// ---------------------------------------------------------------------------
#define G1_ROWS 64
#define G1_KC 64

__global__ __launch_bounds__(256) void gemm1_kernel(const float* __restrict__ x,
                                                    const float* __restrict__ W1,
                                                    const float* __restrict__ dinv,
                                                    float* __restrict__ h1s) {
    __shared__ float Ws[F_IN * HID];            // [k][j], 32 KB
    __shared__ float xs[G1_ROWS][G1_KC + 4];
    const int tid = threadIdx.x;
    const int rowBase = blockIdx.x * G1_ROWS;

#pragma unroll
    for (int it = 0; it < 8; it++) {
        int f = it * 256 + tid;
        ((float4*)Ws)[f] = ((const float4*)W1)[f];
    }

    const int r  = tid >> 2;
    const int j4 = tid & 3;
    float4 acc = make_float4(0.f, 0.f, 0.f, 0.f);

    for (int kc = 0; kc < F_IN; kc += G1_KC) {
        __syncthreads();
#pragma unroll
        for (int it = 0; it < 4; it++) {
            int f = it * 256 + tid;
            int row = f >> 4;
            int c4 = f & 15;
            int grow = rowBase + row;
            if (grow >= N_NODES) grow = N_NODES - 1;
            float4 v = ((const float4*)(x + (long long)grow * F_IN + kc))[c4];
            *((float4*)&xs[row][c4 * 4]) = v;
        }
        __syncthreads();
#pragma unroll
        for (int k = 0; k < G1_KC; k++) {
            float xv = xs[r][k];
            float4 wv = ((const float4*)(Ws + (kc + k) * HID))[j4];
            acc.x += xv * wv.x;
            acc.y += xv * wv.y;
            acc.z += xv * wv.z;
            acc.w += xv * wv.w;
        }
    }
    int grow = rowBase + r;
    if (grow < N_NODES) {
        float dn = dinv[grow];
        acc.x *= dn; acc.y *= dn; acc.z *= dn; acc.w *= dn;
        ((float4*)(h1s + (long long)grow * HID))[j4] = acc;
    }
}

// ---------------------------------------------------------------------------
// Fused layer-1 gather + bias + relu + GEMM2 + rescale:
//   t[n][j]   = relu(b1[j] + dinv[n]*(h1s[n][j] + sum_{src in(n)} h1s[src][j]))
//   h2s[n][c] = dinv[n] * (t[n][:] @ W2[:,c]),  padded to 8 cols (col7 = 0)
// 4 lanes per node; 64 nodes per 256-thread block.
// ---------------------------------------------------------------------------
#define A1_NODES 64

__global__ __launch_bounds__(256) void agg1_gemm2_kernel(const int* __restrict__ rowptr,
                                                         const int* __restrict__ csr_src,
                                                         const float* __restrict__ h1s,
                                                         const float* __restrict__ dinv,
                                                         const float* __restrict__ b1,
                                                         const float* __restrict__ W2,
                                                         float* __restrict__ h2s) {
    __shared__ float W2s[HID][8];                 // col 7 zero-padded
    __shared__ float t_lds[A1_NODES][HID + 1];    // +1: break 16-stride banks
    const int tid = threadIdx.x;
    if (tid < HID * 8) {
        int j = tid >> 3, c = tid & 7;
        W2s[j][c] = (c < CLS) ? W2[j * CLS + c] : 0.f;
    }
    const int ln = tid >> 2;
    const int j4 = tid & 3;
    const int n = blockIdx.x * A1_NODES + ln;
    float dn = 0.f;
    if (n < N_NODES) {
        const int beg = rowptr[n], end = rowptr[n + 1];
        const float4* h4 = (const float4*)h1s;
        float4 s4 = make_float4(0.f, 0.f, 0.f, 0.f);
        for (int k = beg; k < end; k++) {
            int src = csr_src[k];                 // same addr across 4 lanes
            float4 v = h4[(long long)src * 4 + j4];
            s4.x += v.x; s4.y += v.y; s4.z += v.z; s4.w += v.w;
        }
        dn = dinv[n];
        float4 self = h4[(long long)n * 4 + j4];
        float4 bb = ((const float4*)b1)[j4];
        float* tp = &t_lds[ln][j4 * 4];
        tp[0] = fmaxf(bb.x + dn * (self.x + s4.x), 0.f);
        tp[1] = fmaxf(bb.y + dn * (self.y + s4.y), 0.f);
        tp[2] = fmaxf(bb.z + dn * (self.z + s4.z), 0.f);
        tp[3] = fmaxf(bb.w + dn * (self.w + s4.w), 0.f);
    }
    __syncthreads();
    if (n < N_NODES) {
        // lane j4 computes output cols {2*j4, 2*j4+1}
        float a0 = 0.f, a1 = 0.f;
#pragma unroll
        for (int j = 0; j < HID; j++) {
            float v = t_lds[ln][j];
            a0 += v * W2s[j][2 * j4];
            a1 += v * W2s[j][2 * j4 + 1];
        }
        h2s[(long long)n * 8 + 2 * j4]     = dn * a0;   // col7 = 0 via W2s pad
        h2s[(long long)n * 8 + 2 * j4 + 1] = dn * a1;
    }
}

// ---------------------------------------------------------------------------
// Layer-2 gather, writes final out (also resolves the 0xAA poison):
//   out[n][c] = b2[c] + dinv[n]*(h2s[n][c] + sum_{src in(n)} h2s[src][c])
// 8 lanes per node (col 7 is padding); 32 nodes per 256-thread block.
// ---------------------------------------------------------------------------
#define A2_NODES 32

__global__ __launch_bounds__(256) void agg2_gather_kernel(const int* __restrict__ rowptr,
                                                          const int* __restrict__ csr_src,
                                                          const float* __restrict__ h2s,
                                                          const float* __restrict__ dinv,
                                                          const float* __restrict__ b2,
                                                          float* __restrict__ out) {
    const int tid = threadIdx.x;
    const int ln = tid >> 3;
    const int c = tid & 7;
    const int n = blockIdx.x * A2_NODES + ln;
    if (n >= N_NODES) return;
    const int beg = rowptr[n], end = rowptr[n + 1];
    float s = 0.f;
    for (int k = beg; k < end; k++) {
        int src = csr_src[k];                     // same addr across 8 lanes
        s += h2s[(long long)src * 8 + c];
    }
    if (c < CLS)
        out[(long long)n * CLS + c] = b2[c] + dinv[n] * (h2s[(long long)n * 8 + c] + s);
}

// ---------------------------------------------------------------------------
extern "C" void kernel_launch(void* const* d_in, const int* in_sizes, int n_in,
                              void* d_out, int out_size, void* d_ws, size_t ws_size,
                              hipStream_t stream) {
    const float* x    = (const float*)d_in[0];
    const void*  eidx = d_in[1];
    const float* W1   = (const float*)d_in[2];
    const float* b1   = (const float*)d_in[3];
    const float* W2   = (const float*)d_in[4];
    const float* b2   = (const float*)d_in[5];
    float* out = (float*)d_out;
    const long long E = (long long)in_sizes[1] / 2;

    // workspace carve-up (256B aligned); total ~24 MB
    char* ws = (char*)d_ws;
    size_t off = 0;
    auto alloc = [&](size_t bytes) -> void* {
        void* p = ws + off;
        off = (off + bytes + 255) & ~(size_t)255;
        return p;
    };
    int*   flag    = (int*)alloc(4);
    int*   deg     = (int*)alloc((size_t)N_NODES * 4);
    float* dinv    = (float*)alloc((size_t)N_NODES * 4);
    int*   rowptr  = (int*)alloc((size_t)(N_NODES + 1) * 4);
    int*   tmp     = (int*)alloc((size_t)N_NODES * 4);     // reused as cursor
    int*   bsum    = (int*)alloc(1024);
    int*   csr_src = (int*)alloc((size_t)E * 4);
    float* h1s     = (float*)alloc((size_t)N_NODES * HID * 4);
    float* h2s     = (float*)alloc((size_t)N_NODES * 8 * 4);
    int*   cursor  = tmp;   // alias: tmp dead after scan3
    (void)ws_size;

    const int NB = (N_NODES + SCAN_B - 1) / SCAN_B;   // 98

    hipMemsetAsync(deg, 0, (size_t)N_NODES * 4, stream);

    detect_i64_kernel<<<1, 256, 0, stream>>>((const unsigned int*)eidx, flag,
                                             (int)(E < 4096 ? E : 4096));

    deg_kernel<<<(int)((E + 255) / 256), 256, 0, stream>>>(eidx, E, flag, deg);

    dinv_kernel<<<(N_NODES + 255) / 256, 256, 0, stream>>>(deg, dinv);

    scan1_kernel<<<NB, SCAN_B, 0, stream>>>(deg, tmp, bsum, N_NODES);
    scan2_kernel<<<1, 1, 0, stream>>>(bsum, NB, rowptr + N_NODES);
    scan3_kernel<<<NB, SCAN_B, 0, stream>>>(deg, tmp, bsum, rowptr, N_NODES);

    // cursor := rowptr (tmp is dead now; stream-ordered d2d copy is capture-safe)
    hipMemcpyAsync(cursor, rowptr, (size_t)N_NODES * 4, hipMemcpyDeviceToDevice, stream);

    fill_kernel<<<(int)((E + 255) / 256), 256, 0, stream>>>(eidx, E, flag, cursor, csr_src);

    gemm1_kernel<<<(N_NODES + G1_ROWS - 1) / G1_ROWS, 256, 0, stream>>>(x, W1, dinv, h1s);

    agg1_gemm2_kernel<<<(N_NODES + A1_NODES - 1) / A1_NODES, 256, 0, stream>>>(
        rowptr, csr_src, h1s, dinv, b1, W2, h2s);

    agg2_gather_kernel<<<(N_NODES + A2_NODES - 1) / A2_NODES, 256, 0, stream>>>(
        rowptr, csr_src, h2s, dinv, b2, out);
}

// Round 3
// 485.951 us; speedup vs baseline: 4.5303x; 1.7215x over previous
//
#include <hip/hip_runtime.h>

#define N_NODES 100000
#define F_IN 512
#define HID 16
#define CLS 7

#define BK_SHIFT 9
#define BK_NODES 512                       // nodes per bucket
#define NBK ((N_NODES + BK_NODES - 1) / BK_NODES)   // 196

// ---------------------------------------------------------------------------
// Edge-index dtype detection (int64 vs int32, see R0 note).
// ---------------------------------------------------------------------------
__global__ void detect_i64_kernel(const unsigned int* __restrict__ idx32,
                                  int* __restrict__ flag, int n_check) {
    __shared__ unsigned int s;
    if (threadIdx.x == 0) s = 0u;
    __syncthreads();
    unsigned int v = 0u;
    for (int i = threadIdx.x; i < n_check; i += blockDim.x)
        v |= idx32[2 * i + 1];
    atomicOr(&s, v);
    __syncthreads();
    if (threadIdx.x == 0) *flag = (s == 0u) ? 1 : 0;
}

__device__ __forceinline__ void get_edge(const void* eidx, long long E,
                                         long long e, int is64,
                                         int& s, int& d) {
    if (is64) {
        const long long* p = (const long long*)eidx;
        s = (int)p[e];
        d = (int)p[E + e];
    } else {
        const int* p = (const int*)eidx;
        s = p[e];
        d = p[E + e];
    }
}

// ---------------------------------------------------------------------------
// Pass 1: per-bucket edge counts (LDS histogram, one global atomic per
// block per bucket — 200K atomics instead of 3.2M).
// ---------------------------------------------------------------------------
__global__ __launch_bounds__(256) void bin_count_kernel(const void* __restrict__ eidx,
                                                        long long E,
                                                        const int* __restrict__ flag,
                                                        int* __restrict__ bucket_cnt) {
    __shared__ int h[NBK];
    const int is64 = *flag;
    for (int i = threadIdx.x; i < NBK; i += 256) h[i] = 0;
    __syncthreads();
    long long stride = (long long)gridDim.x * blockDim.x;
    for (long long e = (long long)blockIdx.x * blockDim.x + threadIdx.x; e < E; e += stride) {
        int d;
        if (is64) d = (int)((const long long*)eidx)[E + e];
        else      d = ((const int*)eidx)[E + e];
        atomicAdd(&h[d >> BK_SHIFT], 1);
    }
    __syncthreads();
    for (int i = threadIdx.x; i < NBK; i += 256)
        if (h[i]) atomicAdd(&bucket_cnt[i], h[i]);
}

// ---------------------------------------------------------------------------
// Pass 2: exclusive scan of 196 bucket counts (single block).
// Also initializes bucket_cursor and rowptr[N].
// ---------------------------------------------------------------------------
__global__ __launch_bounds__(256) void bucket_scan_kernel(const int* __restrict__ bucket_cnt,
                                                          int* __restrict__ bucket_base,
                                                          int* __restrict__ bucket_cursor,
                                                          int* __restrict__ rowptr,
                                                          long long E) {
    __shared__ int s[256];
    int tid = threadIdx.x;
    int v = (tid < NBK) ? bucket_cnt[tid] : 0;
    s[tid] = v;
    __syncthreads();
    for (int off = 1; off < 256; off <<= 1) {
        int a = (tid >= off) ? s[tid - off] : 0;
        __syncthreads();
        s[tid] += a;
        __syncthreads();
    }
    if (tid < NBK) {
        int e = s[tid] - v;
        bucket_base[tid] = e;
        bucket_cursor[tid] = e;
    }
    if (tid == 0) {
        bucket_base[NBK] = (int)E;
        rowptr[N_NODES] = (int)E;
    }
}

// ---------------------------------------------------------------------------
// Pass 3: LDS-staged multisplit. Each block bins a 16K-edge tile bucket-major
// in LDS, reserves global ranges (1 atomic/block/bucket), flushes with
// contiguous coalesced runs. Edge packed to 4B: (dst&511)<<17 | src.
// ---------------------------------------------------------------------------
#define SC_T 1024
#define SC_TILE 16384

__global__ __launch_bounds__(SC_T) void bin_scatter_kernel(const void* __restrict__ eidx,
                                                           long long E,
                                                           const int* __restrict__ flag,
                                                           int* __restrict__ bucket_cursor,
                                                           unsigned int* __restrict__ binned) {
    __shared__ unsigned int stage[SC_TILE];    // 64 KB
    __shared__ unsigned char stageb[SC_TILE];  // 16 KB: bucket id per slot
    __shared__ int hist[NBK];
    __shared__ int excl[NBK];
    __shared__ int curs[NBK];
    __shared__ int gbase[NBK];
    __shared__ int scanv[256];
    const int is64 = *flag;
    const int tid = threadIdx.x;
    const long long tileBeg = (long long)blockIdx.x * SC_TILE;
    long long rem = E - tileBeg;
    const int cnt = (int)(rem < SC_TILE ? rem : SC_TILE);

    for (int i = tid; i < NBK; i += SC_T) hist[i] = 0;
    __syncthreads();
    for (int i = tid; i < cnt; i += SC_T) {
        long long e = tileBeg + i;
        int d;
        if (is64) d = (int)((const long long*)eidx)[E + e];
        else      d = ((const int*)eidx)[E + e];
        atomicAdd(&hist[d >> BK_SHIFT], 1);
    }
    __syncthreads();
    if (tid < 256) scanv[tid] = (tid < NBK) ? hist[tid] : 0;
    __syncthreads();
    for (int off = 1; off < 256; off <<= 1) {
        int a = 0;
        if (tid < 256 && tid >= off) a = scanv[tid - off];
        __syncthreads();
        if (tid < 256) scanv[tid] += a;
        __syncthreads();
    }
    if (tid < NBK) {
        int e = scanv[tid] - hist[tid];
        excl[tid] = e;
        curs[tid] = e;
    }
    __syncthreads();
    for (int i = tid; i < cnt; i += SC_T) {
        long long e = tileBeg + i;
        int s, d;
        get_edge(eidx, E, e, is64, s, d);
        int b = d >> BK_SHIFT;
        int pos = atomicAdd(&curs[b], 1);
        stage[pos] = ((unsigned int)(d & (BK_NODES - 1)) << 17) | (unsigned int)s;
        stageb[pos] = (unsigned char)b;
    }
    __syncthreads();
    if (tid < NBK) gbase[tid] = hist[tid] ? atomicAdd(&bucket_cursor[tid], hist[tid]) : 0;
    __syncthreads();
    // bucket-major staging -> long coalesced runs into each bucket's range
    for (int i = tid; i < cnt; i += SC_T) {
        int b = stageb[i];
        binned[gbase[b] + (i - excl[b])] = stage[i];
    }
}

// ---------------------------------------------------------------------------
// Pass 4: per-bucket CSR finalize, fully in LDS. Produces deg->dinv and
// rowptr for free; reorders binned IN PLACE into csr_src (src per slot).
// ---------------------------------------------------------------------------
#define CB_T 512
#define CB_CAP 24576   // avg bucket = 16.4K, sigma ~128; 24K is ~60 sigma

__global__ __launch_bounds__(CB_T) void csr_build_kernel(const int* __restrict__ bucket_base,
                                                         unsigned int* __restrict__ binned,
                                                         float* __restrict__ dinv,
                                                         int* __restrict__ rowptr) {
    __shared__ unsigned int stage[CB_CAP];   // 96 KB
    __shared__ int hist[BK_NODES];
    __shared__ int scanv[BK_NODES];
    __shared__ int curs[BK_NODES];
    const int tid = threadIdx.x;
    const int b = blockIdx.x;
    const int beg = bucket_base[b];
    int cnt = bucket_base[b + 1] - beg;
    if (cnt > CB_CAP) cnt = CB_CAP;          // unreachable for this input
    for (int i = tid; i < BK_NODES; i += CB_T) hist[i] = 0;
    __syncthreads();
    for (int i = tid; i < cnt; i += CB_T)
        atomicAdd(&hist[binned[beg + i] >> 17], 1);
    __syncthreads();
    scanv[tid] = hist[tid];                  // CB_T == BK_NODES == 512
    __syncthreads();
    for (int off = 1; off < BK_NODES; off <<= 1) {
        int a = (tid >= off) ? scanv[tid - off] : 0;
        __syncthreads();
        scanv[tid] += a;
        __syncthreads();
    }
    {
        int e = scanv[tid] - hist[tid];
        curs[tid] = e;
        int g = b * BK_NODES + tid;
        if (g < N_NODES) {
            rowptr[g] = beg + e;
            dinv[g] = rsqrtf((float)(hist[tid] + 1));   // +1 self-loop
        }
    }
    __syncthreads();
    for (int i = tid; i < cnt; i += CB_T) {
        unsigned int v = binned[beg + i];
        int pos = atomicAdd(&curs[(int)(v >> 17)], 1);
        stage[pos] = v & 0x1FFFFu;
    }
    __syncthreads();
    for (int i = tid; i < cnt; i += CB_T)
        binned[beg + i] = stage[i];          // in place: binned becomes csr_src
}

// ---------------------------------------------------------------------------
// GEMM1: h1s[i][16] = (x[i][512] @ W1[512][16]) * dinv[i]   (fp32, HBM-bound)
// ---------------------------------------------------------------------------
#define G1_ROWS 64
#define G1_KC 64

__global__ __launch_bounds__(256) void gemm1_kernel(const float* __restrict__ x,
                                                    const float* __restrict__ W1,
                                                    const float* __restrict__ dinv,
                                                    float* __restrict__ h1s) {
    __shared__ float Ws[F_IN * HID];            // 32 KB
    __shared__ float xs[G1_ROWS][G1_KC + 4];
    const int tid = threadIdx.x;
    const int rowBase = blockIdx.x * G1_ROWS;

#pragma unroll
    for (int it = 0; it < 8; it++) {
        int f = it * 256 + tid;
        ((float4*)Ws)[f] = ((const float4*)W1)[f];
    }

    const int r  = tid >> 2;
    const int j4 = tid & 3;
    float4 acc = make_float4(0.f, 0.f, 0.f, 0.f);

    for (int kc = 0; kc < F_IN; kc += G1_KC) {
        __syncthreads();
#pragma unroll
        for (int it = 0; it < 4; it++) {
            int f = it * 256 + tid;
            int row = f >> 4;
            int c4 = f & 15;
            int grow = rowBase + row;
            if (grow >= N_NODES) grow = N_NODES - 1;
            float4 v = ((const float4*)(x + (long long)grow * F_IN + kc))[c4];
            *((float4*)&xs[row][c4 * 4]) = v;
        }
        __syncthreads();
#pragma unroll
        for (int k = 0; k < G1_KC; k++) {
            float xv = xs[r][k];
            float4 wv = ((const float4*)(Ws + (kc + k) * HID))[j4];
            acc.x += xv * wv.x;
            acc.y += xv * wv.y;
            acc.z += xv * wv.z;
            acc.w += xv * wv.w;
        }
    }
    int grow = rowBase + r;
    if (grow < N_NODES) {
        float dn = dinv[grow];
        acc.x *= dn; acc.y *= dn; acc.z *= dn; acc.w *= dn;
        ((float4*)(h1s + (long long)grow * HID))[j4] = acc;
    }
}

// ---------------------------------------------------------------------------
// Fused layer-1 gather + bias + relu + GEMM2 + rescale -> h2s[N][8]
// ---------------------------------------------------------------------------
#define A1_NODES 64

__global__ __launch_bounds__(256) void agg1_gemm2_kernel(const int* __restrict__ rowptr,
                                                         const int* __restrict__ csr_src,
                                                         const float* __restrict__ h1s,
                                                         const float* __restrict__ dinv,
                                                         const float* __restrict__ b1,
                                                         const float* __restrict__ W2,
                                                         float* __restrict__ h2s) {
    __shared__ float W2s[HID][8];
    __shared__ float t_lds[A1_NODES][HID + 1];
    const int tid = threadIdx.x;
    if (tid < HID * 8) {
        int j = tid >> 3, c = tid & 7;
        W2s[j][c] = (c < CLS) ? W2[j * CLS + c] : 0.f;
    }
    const int ln = tid >> 2;
    const int j4 = tid & 3;
    const int n = blockIdx.x * A1_NODES + ln;
    float dn = 0.f;
    if (n < N_NODES) {
        const int beg = rowptr[n], end = rowptr[n + 1];
        const float4* h4 = (const float4*)h1s;
        float4 s4 = make_float4(0.f, 0.f, 0.f, 0.f);
        for (int k = beg; k < end; k++) {
            int src = csr_src[k];
            float4 v = h4[(long long)src * 4 + j4];
            s4.x += v.x; s4.y += v.y; s4.z += v.z; s4.w += v.w;
        }
        dn = dinv[n];
        float4 self = h4[(long long)n * 4 + j4];
        float4 bb = ((const float4*)b1)[j4];
        float* tp = &t_lds[ln][j4 * 4];
        tp[0] = fmaxf(bb.x + dn * (self.x + s4.x), 0.f);
        tp[1] = fmaxf(bb.y + dn * (self.y + s4.y), 0.f);
        tp[2] = fmaxf(bb.z + dn * (self.z + s4.z), 0.f);
        tp[3] = fmaxf(bb.w + dn * (self.w + s4.w), 0.f);
    }
    __syncthreads();
    if (n < N_NODES) {
        float a0 = 0.f, a1 = 0.f;
#pragma unroll
        for (int j = 0; j < HID; j++) {
            float v = t_lds[ln][j];
            a0 += v * W2s[j][2 * j4];
            a1 += v * W2s[j][2 * j4 + 1];
        }
        h2s[(long long)n * 8 + 2 * j4]     = dn * a0;
        h2s[(long long)n * 8 + 2 * j4 + 1] = dn * a1;
    }
}

// ---------------------------------------------------------------------------
// Layer-2 gather -> final out
// ---------------------------------------------------------------------------
#define A2_NODES 32

__global__ __launch_bounds__(256) void agg2_gather_kernel(const int* __restrict__ rowptr,
                                                          const int* __restrict__ csr_src,
                                                          const float* __restrict__ h2s,
                                                          const float* __restrict__ dinv,
                                                          const float* __restrict__ b2,
                                                          float* __restrict__ out) {
    const int tid = threadIdx.x;
    const int ln = tid >> 3;
    const int c = tid & 7;
    const int n = blockIdx.x * A2_NODES + ln;
    if (n >= N_NODES) return;
    const int beg = rowptr[n], end = rowptr[n + 1];
    float s = 0.f;
    for (int k = beg; k < end; k++) {
        int src = csr_src[k];
        s += h2s[(long long)src * 8 + c];
    }
    if (c < CLS)
        out[(long long)n * CLS + c] = b2[c] + dinv[n] * (h2s[(long long)n * 8 + c] + s);
}

// ---------------------------------------------------------------------------
extern "C" void kernel_launch(void* const* d_in, const int* in_sizes, int n_in,
                              void* d_out, int out_size, void* d_ws, size_t ws_size,
                              hipStream_t stream) {
    const float* x    = (const float*)d_in[0];
    const void*  eidx = d_in[1];
    const float* W1   = (const float*)d_in[2];
    const float* b1   = (const float*)d_in[3];
    const float* W2   = (const float*)d_in[4];
    const float* b2   = (const float*)d_in[5];
    float* out = (float*)d_out;
    const long long E = (long long)in_sizes[1] / 2;

    // workspace carve-up (256B aligned); total ~23 MB
    char* ws = (char*)d_ws;
    size_t off = 0;
    auto alloc = [&](size_t bytes) -> void* {
        void* p = ws + off;
        off = (off + bytes + 255) & ~(size_t)255;
        return p;
    };
    int*          flag          = (int*)alloc(4);
    int*          bucket_cnt    = (int*)alloc((size_t)NBK * 4);
    int*          bucket_base   = (int*)alloc((size_t)(NBK + 1) * 4);
    int*          bucket_cursor = (int*)alloc((size_t)NBK * 4);
    unsigned int* binned        = (unsigned int*)alloc((size_t)E * 4);  // -> csr_src
    int*          rowptr        = (int*)alloc((size_t)(N_NODES + 1) * 4);
    float*        dinv          = (float*)alloc((size_t)N_NODES * 4);
    float*        h1s           = (float*)alloc((size_t)N_NODES * HID * 4);
    float*        h2s           = (float*)alloc((size_t)N_NODES * 8 * 4);
    (void)ws_size;

    hipMemsetAsync(bucket_cnt, 0, (size_t)NBK * 4, stream);

    detect_i64_kernel<<<1, 256, 0, stream>>>((const unsigned int*)eidx, flag,
                                             (int)(E < 4096 ? E : 4096));

    bin_count_kernel<<<1024, 256, 0, stream>>>(eidx, E, flag, bucket_cnt);

    bucket_scan_kernel<<<1, 256, 0, stream>>>(bucket_cnt, bucket_base, bucket_cursor,
                                              rowptr, E);

    bin_scatter_kernel<<<(int)((E + SC_TILE - 1) / SC_TILE), SC_T, 0, stream>>>(
        eidx, E, flag, bucket_cursor, binned);

    csr_build_kernel<<<NBK, CB_T, 0, stream>>>(bucket_base, binned, dinv, rowptr);

    gemm1_kernel<<<(N_NODES + G1_ROWS - 1) / G1_ROWS, 256, 0, stream>>>(x, W1, dinv, h1s);

    const int* csr_src = (const int*)binned;
    agg1_gemm2_kernel<<<(N_NODES + A1_NODES - 1) / A1_NODES, 256, 0, stream>>>(
        rowptr, csr_src, h1s, dinv, b1, W2, h2s);

    agg2_gather_kernel<<<(N_NODES + A2_NODES - 1) / A2_NODES, 256, 0, stream>>>(
        rowptr, csr_src, h2s, dinv, b2, out);
}